// Round 2
// baseline (2347.932 us; speedup 1.0000x reference)
//
#include <hip/hip_runtime.h>
#include <math.h>

#define BB 8
#define NN 2048
#define CC 128
#define KNB 16
#define BN (BB*NN)
#define GPTS 16

__device__ __forceinline__ float silu_f(float x) { return x / (1.0f + expf(-x)); }

// ---------------------------------------------------------------------------
// Kernel 1: kNN (one block per query point). Distances computed in DOUBLE:
// fp32 inputs -> f64 products are exact, so ordering matches the true
// (and any f64-numpy-reference) ordering bit-for-bit. Lower-index tie-break
// matches lax.top_k set semantics.
// ---------------------------------------------------------------------------
__global__ __launch_bounds__(256) void knn_kernel(const float* __restrict__ x,
                                                  int* __restrict__ idx) {
  const int bn = blockIdx.x;
  const int b = bn >> 11;
  const int n = bn & (NN - 1);
  const int tid = threadIdx.x;
  __shared__ double d2[NN];
  __shared__ double rv[4];
  __shared__ int    ri[4];

  const float* xb = x + (size_t)b * NN * 3;
  const double xn0 = (double)xb[n*3+0], xn1 = (double)xb[n*3+1], xn2 = (double)xb[n*3+2];
  const double sqn = xn0*xn0 + xn1*xn1 + xn2*xn2;

  for (int m = tid; m < NN; m += 256) {
    double a0 = (double)xb[m*3+0], a1 = (double)xb[m*3+1], a2 = (double)xb[m*3+2];
    double sqm = a0*a0 + a1*a1 + a2*a2;
    double dot = xn0*a0 + xn1*a1 + xn2*a2;
    double d = sqn + sqm - 2.0*dot;
    d2[m] = (m == n) ? (double)INFINITY : d;
  }
  __syncthreads();

  const int lane = tid & 63, wave = tid >> 6;
  for (int t = 0; t < KNB; ++t) {
    double bv = (double)INFINITY; int bi = 0x7fffffff;
    for (int m = tid; m < NN; m += 256) {
      double vv = d2[m];
      if (vv < bv) { bv = vv; bi = m; }
    }
    #pragma unroll
    for (int off = 32; off > 0; off >>= 1) {
      double ov = __shfl_down(bv, off, 64);
      int    oi = __shfl_down(bi, off, 64);
      if (ov < bv || (ov == bv && oi < bi)) { bv = ov; bi = oi; }
    }
    if (lane == 0) { rv[wave] = bv; ri[wave] = bi; }
    __syncthreads();
    if (tid == 0) {
      double fb = rv[0]; int fi = ri[0];
      #pragma unroll
      for (int w2 = 1; w2 < 4; ++w2) {
        double ov = rv[w2]; int oi = ri[w2];
        if (ov < fb || (ov == fb && oi < fi)) { fb = ov; fi = oi; }
      }
      idx[(size_t)bn * KNB + t] = fi;
      d2[fi] = (double)INFINITY;
    }
    __syncthreads();
  }
}

// ---------------------------------------------------------------------------
// Kernel 2: Q/K/U = vn_linear(v, W*) + per-point qn/kn (mean channel norms).
// 384 threads: thread owns (mat, o); W row in registers; v read at
// block-uniform addresses (-> scalar loads); pure v_fma inner loop.
// ---------------------------------------------------------------------------
__global__ __launch_bounds__(384) void vn_linear_kernel(
    const float* __restrict__ v,
    const float* __restrict__ Wq, const float* __restrict__ Wk, const float* __restrict__ Wu,
    float* __restrict__ Q, float* __restrict__ Kt, float* __restrict__ U,
    float* __restrict__ qn, float* __restrict__ kn)
{
  const int tid = threadIdx.x;
  const int mat = tid >> 7;
  const int o = tid & 127;
  const float* W = (mat == 0) ? Wq : ((mat == 1) ? Wk : Wu);
  float* Out = (mat == 0) ? Q : ((mat == 1) ? Kt : U);

  float w[CC];
  {
    const float4* Wr = (const float4*)(W + (size_t)o * CC);
    #pragma unroll
    for (int i = 0; i < CC/4; ++i) {
      float4 t4 = Wr[i];
      w[4*i+0] = t4.x; w[4*i+1] = t4.y; w[4*i+2] = t4.z; w[4*i+3] = t4.w;
    }
  }

  __shared__ float red[6];
  for (int p = 0; p < GPTS; ++p) {
    const int point = blockIdx.x * GPTS + p;
    const float* __restrict__ vp = v + (size_t)point * (CC*3);
    float a0 = 0.f, a1 = 0.f, a2 = 0.f;
    #pragma unroll
    for (int c = 0; c < CC; ++c) {
      const float wv = w[c];
      a0 = fmaf(wv, vp[c*3+0], a0);
      a1 = fmaf(wv, vp[c*3+1], a1);
      a2 = fmaf(wv, vp[c*3+2], a2);
    }
    float* op = Out + (size_t)point * (CC*3) + o*3;
    op[0] = a0; op[1] = a1; op[2] = a2;

    const float nrm = sqrtf(a0*a0 + a1*a1 + a2*a2);
    float s = nrm;
    #pragma unroll
    for (int off = 32; off > 0; off >>= 1) s += __shfl_down(s, off, 64);
    if ((tid & 63) == 0) red[tid >> 6] = s;
    __syncthreads();
    if (tid == 0)   qn[point] = (red[0] + red[1]) * (1.0f/128.0f);
    if (tid == 128) kn[point] = (red[2] + red[3]) * (1.0f/128.0f);
    __syncthreads();
  }
}

// ---------------------------------------------------------------------------
// Kernel 3: attention + message + VN layer norm + clamp. One block per point.
// ---------------------------------------------------------------------------
__global__ __launch_bounds__(256) void attn_kernel(
    const float* __restrict__ x, const int* __restrict__ idx,
    const float* __restrict__ Q, const float* __restrict__ Kt, const float* __restrict__ U,
    const float* __restrict__ qn, const float* __restrict__ kn,
    const float* __restrict__ W1, const float* __restrict__ b1,
    const float* __restrict__ W2, const float* __restrict__ b2,
    const float* __restrict__ W3, const float* __restrict__ b3,
    const float* __restrict__ gam, const float* __restrict__ bet,
    float* __restrict__ out)
{
  const int bn = blockIdx.x;
  const int b = bn >> 11;
  const int tid = threadIdx.x;

  __shared__ __align__(16) float qs[CC*3];
  __shared__ int   nbr[KNB];
  __shared__ float sfeat[KNB][4];
  __shared__ float h1s[KNB][33];
  __shared__ float logits[KNB];
  __shared__ float attnw[KNB];
  __shared__ float red[4];
  __shared__ float red2[4];

  const float* Qp = Q + (size_t)bn * (CC*3);
  if (tid < 96) ((float4*)qs)[tid] = ((const float4*)Qp)[tid];
  if (tid < KNB) nbr[tid] = idx[(size_t)bn * KNB + tid];
  __syncthreads();

  // Phase 1: Q.K dots (16 lanes per neighbor) + edge features
  {
    const int lane = tid & 63, wave = tid >> 6;
    const int kk = wave * 4 + (lane >> 4);
    const int sub = lane & 15;
    const int j = nbr[kk];
    const float* Kp = Kt + ((size_t)(b * NN + j)) * (CC*3);
    float acc = 0.f;
    #pragma unroll
    for (int q4 = 0; q4 < 6; ++q4) {
      const int off = sub * 24 + q4 * 4;
      float4 kv = *(const float4*)(Kp + off);
      acc += qs[off+0]*kv.x + qs[off+1]*kv.y + qs[off+2]*kv.z + qs[off+3]*kv.w;
    }
    #pragma unroll
    for (int off = 8; off > 0; off >>= 1) acc += __shfl_down(acc, off, 16);
    if (sub == 0) {
      const float xn0 = x[(size_t)bn*3+0], xn1 = x[(size_t)bn*3+1], xn2 = x[(size_t)bn*3+2];
      const size_t xj = (size_t)(b * NN + j) * 3;
      const float dx = xn0 - x[xj+0], dy = xn1 - x[xj+1], dz = xn2 - x[xj+2];
      sfeat[kk][0] = qn[bn];
      sfeat[kk][1] = kn[b * NN + j];
      sfeat[kk][2] = acc * (1.0f/128.0f);
      sfeat[kk][3] = sqrtf(dx*dx + dy*dy + dz*dz);
    }
  }
  __syncthreads();

  // Phase 2: edge MLP (16 neighbors x 16 threads; 2 hidden units each)
  {
    const int k2 = tid >> 4;
    const int h = tid & 15;
    const float s0 = sfeat[k2][0], s1 = sfeat[k2][1], s2 = sfeat[k2][2], s3 = sfeat[k2][3];
    float u0 = b1[h]    + W1[h*4+0]*s0 + W1[h*4+1]*s1 + W1[h*4+2]*s2 + W1[h*4+3]*s3;
    float u1 = b1[h+16] + W1[(h+16)*4+0]*s0 + W1[(h+16)*4+1]*s1 + W1[(h+16)*4+2]*s2 + W1[(h+16)*4+3]*s3;
    h1s[k2][h]    = silu_f(u0);
    h1s[k2][h+16] = silu_f(u1);
  }
  __syncthreads();
  {
    const int k2 = tid >> 4;
    const int h = tid & 15;
    float a0 = b2[h], a1 = b2[h+16];
    #pragma unroll
    for (int c = 0; c < 32; ++c) {
      const float hv = h1s[k2][c];
      a0 = fmaf(W2[h*32+c], hv, a0);
      a1 = fmaf(W2[(h+16)*32+c], hv, a1);
    }
    a0 = silu_f(a0); a1 = silu_f(a1);
    float part = W3[h]*a0 + W3[h+16]*a1;
    #pragma unroll
    for (int off = 8; off > 0; off >>= 1) part += __shfl_down(part, off, 16);
    if (h == 0) {
      const float lg = part + b3[0];
      logits[k2] = fminf(fmaxf(lg, -10.0f), 10.0f);
    }
  }
  __syncthreads();

  // Phase 3: softmax over the 16 neighbors (lanes 0..15 of wave 0)
  if (tid < KNB) {
    const float l = logits[tid];
    float m = l;
    #pragma unroll
    for (int off = 8; off > 0; off >>= 1) m = fmaxf(m, __shfl_xor(m, off, 16));
    const float e = expf(l - m);
    float ssum = e;
    #pragma unroll
    for (int off = 8; off > 0; off >>= 1) ssum += __shfl_xor(ssum, off, 16);
    attnw[tid] = e / ssum;
  }
  __syncthreads();

  // Phase 4: message + residual + VN layer norm + clamp (thread = channel o)
  float o0 = 0.f, o1 = 0.f, o2 = 0.f, nrm = 0.f;
  const bool act = tid < CC;
  if (act) {
    const int o = tid;
    float m0 = 0.f, m1 = 0.f, m2 = 0.f;
    #pragma unroll
    for (int k2 = 0; k2 < KNB; ++k2) {
      const int j = nbr[k2];
      const float* Up = U + ((size_t)(b * NN + j)) * (CC*3) + o*3;
      const float a = attnw[k2];
      m0 = fmaf(a, Up[0], m0);
      m1 = fmaf(a, Up[1], m1);
      m2 = fmaf(a, Up[2], m2);
    }
    o0 = qs[o*3+0] + 0.5f*m0;
    o1 = qs[o*3+1] + 0.5f*m1;
    o2 = qs[o*3+2] + 0.5f*m2;
    nrm = fmaxf(sqrtf(o0*o0 + o1*o1 + o2*o2), 1e-6f);
  }
  {
    float s = nrm;
    #pragma unroll
    for (int off = 32; off > 0; off >>= 1) s += __shfl_down(s, off, 64);
    if ((tid & 63) == 0) red[tid >> 6] = s;
  }
  __syncthreads();
  const float mean = (red[0] + red[1] + red[2] + red[3]) * (1.0f/128.0f);
  const float dv = act ? (nrm - mean) : 0.f;
  {
    float s = dv * dv;
    #pragma unroll
    for (int off = 32; off > 0; off >>= 1) s += __shfl_down(s, off, 64);
    if ((tid & 63) == 0) red2[tid >> 6] = s;
  }
  __syncthreads();
  const float var = (red2[0] + red2[1] + red2[2] + red2[3]) * (1.0f/127.0f);
  const float stdv = fmaxf(sqrtf(var), 1e-6f);

  if (act) {
    const int o = tid;
    const float ns = (nrm - mean) / stdv * gam[o] + bet[o];
    const float sc1 = fmaxf(ns, 1e-6f) / nrm;
    float f0 = o0*sc1, f1 = o1*sc1, f2 = o2*sc1;
    const float n2 = fmaxf(sqrtf(f0*f0 + f1*f1 + f2*f2), 1e-6f);
    const float sc2 = fminf(50.0f / n2, 1.0f);
    float* op = out + (size_t)bn * (CC*3) + o*3;
    op[0] = f0*sc2; op[1] = f1*sc2; op[2] = f2*sc2;
  }
}

// ---------------------------------------------------------------------------
extern "C" void kernel_launch(void* const* d_in, const int* in_sizes, int n_in,
                              void* d_out, int out_size, void* d_ws, size_t ws_size,
                              hipStream_t stream) {
  (void)in_sizes; (void)n_in; (void)out_size; (void)ws_size;
  const float* x   = (const float*)d_in[0];
  const float* v   = (const float*)d_in[1];
  const float* Wq  = (const float*)d_in[2];
  const float* Wk  = (const float*)d_in[3];
  const float* Wu  = (const float*)d_in[4];
  const float* W1  = (const float*)d_in[5];
  const float* b1  = (const float*)d_in[6];
  const float* W2  = (const float*)d_in[7];
  const float* b2  = (const float*)d_in[8];
  const float* W3  = (const float*)d_in[9];
  const float* b3  = (const float*)d_in[10];
  const float* gam = (const float*)d_in[11];
  const float* bet = (const float*)d_in[12];
  float* out = (float*)d_out;

  char* ws = (char*)d_ws;
  int*   idx = (int*)ws;                                  // BN*16 ints (1 MB)
  float* Q   = (float*)(ws + (size_t)BN * KNB * 4);       // BN*384 floats
  float* Kt  = Q  + (size_t)BN * CC * 3;
  float* U   = Kt + (size_t)BN * CC * 3;
  float* qn  = U  + (size_t)BN * CC * 3;
  float* kn  = qn + BN;

  knn_kernel<<<BN, 256, 0, stream>>>(x, idx);
  vn_linear_kernel<<<BN / GPTS, 384, 0, stream>>>(v, Wq, Wk, Wu, Q, Kt, U, qn, kn);
  attn_kernel<<<BN, 256, 0, stream>>>(x, idx, Q, Kt, U, qn, kn,
                                      W1, b1, W2, b2, W3, b3, gam, bet, out);
}

// Round 3
// 661.104 us; speedup vs baseline: 3.5515x; 3.5515x over previous
//
#include <hip/hip_runtime.h>
#include <math.h>

#define BB 8
#define NN 2048
#define CC 128
#define KNB 16
#define BN (BB*NN)
#define PT 16          // points per GEMM tile
#define WSROW 132      // padded LDS row for W (16B-aligned, spreads banks)

__device__ __forceinline__ float silu_f(float x) { return x / (1.0f + expf(-x)); }

// ---------------------------------------------------------------------------
// Kernel 1: kNN (one block per query point). Distances computed in DOUBLE:
// fp32 inputs -> f64 products are exact, so ordering matches the f64 numpy
// reference bit-for-bit. Lower-index tie-break matches lax.top_k set.
// ---------------------------------------------------------------------------
__global__ __launch_bounds__(256) void knn_kernel(const float* __restrict__ x,
                                                  int* __restrict__ idx) {
  const int bn = blockIdx.x;
  const int b = bn >> 11;
  const int n = bn & (NN - 1);
  const int tid = threadIdx.x;
  __shared__ double d2[NN];
  __shared__ double rv[4];
  __shared__ int    ri[4];

  const float* xb = x + (size_t)b * NN * 3;
  const double xn0 = (double)xb[n*3+0], xn1 = (double)xb[n*3+1], xn2 = (double)xb[n*3+2];
  const double sqn = xn0*xn0 + xn1*xn1 + xn2*xn2;

  for (int m = tid; m < NN; m += 256) {
    double a0 = (double)xb[m*3+0], a1 = (double)xb[m*3+1], a2 = (double)xb[m*3+2];
    double sqm = a0*a0 + a1*a1 + a2*a2;
    double dot = xn0*a0 + xn1*a1 + xn2*a2;
    double d = sqn + sqm - 2.0*dot;
    d2[m] = (m == n) ? (double)INFINITY : d;
  }
  __syncthreads();

  const int lane = tid & 63, wave = tid >> 6;
  for (int t = 0; t < KNB; ++t) {
    double bv = (double)INFINITY; int bi = 0x7fffffff;
    for (int m = tid; m < NN; m += 256) {
      double vv = d2[m];
      if (vv < bv) { bv = vv; bi = m; }
    }
    #pragma unroll
    for (int off = 32; off > 0; off >>= 1) {
      double ov = __shfl_down(bv, off, 64);
      int    oi = __shfl_down(bi, off, 64);
      if (ov < bv || (ov == bv && oi < bi)) { bv = ov; bi = oi; }
    }
    if (lane == 0) { rv[wave] = bv; ri[wave] = bi; }
    __syncthreads();
    if (tid == 0) {
      double fb = rv[0]; int fi = ri[0];
      #pragma unroll
      for (int w2 = 1; w2 < 4; ++w2) {
        double ov = rv[w2]; int oi = ri[w2];
        if (ov < fb || (ov == fb && oi < fi)) { fb = ov; fi = oi; }
      }
      idx[(size_t)bn * KNB + t] = fi;
      d2[fi] = (double)INFINITY;
    }
    __syncthreads();
  }
}

// ---------------------------------------------------------------------------
// Kernel 2: Q/K/U as LDS-tiled fp32 GEMM. W fully in LDS (Ws[c][o], padded
// row), V tile (16 points x 128c x 3d) in Vs[c][p*4+d]. Thread = (og, p):
// 8 o x 3 d = 24 accumulators. Register prefetch of next tile overlaps the
// k-loop. qn/kn (mean channel norms) computed in the epilogue.
// ---------------------------------------------------------------------------
__global__ __launch_bounds__(256) void vn_linear_gemm(
    const float* __restrict__ v,
    const float* __restrict__ Wq, const float* __restrict__ Wk, const float* __restrict__ Wu,
    float* __restrict__ Q, float* __restrict__ Kt, float* __restrict__ U,
    float* __restrict__ qn, float* __restrict__ kn)
{
  const int mat = blockIdx.y;
  const float* __restrict__ W = (mat == 0) ? Wq : ((mat == 1) ? Wk : Wu);
  float* __restrict__ Out = (mat == 0) ? Q : ((mat == 1) ? Kt : U);

  __shared__ float Ws[CC][WSROW];   // 67.6 KB: [c][o]
  __shared__ float Vs[CC][PT*4];    // 32 KB:   [c][p*4+d]

  const int tid = threadIdx.x;
  const int og = tid & 15;          // o = og*8 .. og*8+7
  const int p  = tid >> 4;          // point within tile
  const int obase = og * 8;

  // Load W[o][c] -> Ws[c][o] (one-time; coalesced global, stride-1-bank LDS writes)
  for (int i = tid; i < CC*CC; i += 256) {
    const int o = i >> 7, c = i & 127;
    Ws[c][o] = W[i];
  }

  float pre[24];
  const int t0 = blockIdx.x;        // tiles t0, t0+256, t0+512, t0+768
  {
    const float4* src = (const float4*)(v + (size_t)t0 * PT * (CC*3));
    #pragma unroll
    for (int it = 0; it < 6; ++it) {
      float4 f = src[tid + it*256];
      pre[it*4+0]=f.x; pre[it*4+1]=f.y; pre[it*4+2]=f.z; pre[it*4+3]=f.w;
    }
  }

  for (int tt = 0; tt < 4; ++tt) {
    const int tile = t0 + tt*256;
    __syncthreads();                // Vs free to overwrite (covers Ws on tt=0)
    #pragma unroll
    for (int it = 0; it < 6; ++it) {
      #pragma unroll
      for (int j = 0; j < 4; ++j) {
        const int g = (tid + it*256)*4 + j;
        const int pp = g / 384;
        const int r  = g - pp*384;
        const int c  = r / 3;
        const int d  = r - c*3;
        Vs[c][pp*4 + d] = pre[it*4+j];
      }
    }
    __syncthreads();

    if (tt < 3) {
      const float4* src = (const float4*)(v + (size_t)(tile + 256) * PT * (CC*3));
      #pragma unroll
      for (int it = 0; it < 6; ++it) {
        float4 f = src[tid + it*256];
        pre[it*4+0]=f.x; pre[it*4+1]=f.y; pre[it*4+2]=f.z; pre[it*4+3]=f.w;
      }
    }

    float acc[24];
    #pragma unroll
    for (int i = 0; i < 24; ++i) acc[i] = 0.f;

    #pragma unroll 4
    for (int c = 0; c < CC; ++c) {
      const float4 w0 = *(const float4*)&Ws[c][obase];
      const float4 w1 = *(const float4*)&Ws[c][obase+4];
      const float4 vv = *(const float4*)&Vs[c][p*4];
      const float wv[8] = {w0.x, w0.y, w0.z, w0.w, w1.x, w1.y, w1.z, w1.w};
      #pragma unroll
      for (int o = 0; o < 8; ++o) {
        acc[o*3+0] = fmaf(wv[o], vv.x, acc[o*3+0]);
        acc[o*3+1] = fmaf(wv[o], vv.y, acc[o*3+1]);
        acc[o*3+2] = fmaf(wv[o], vv.z, acc[o*3+2]);
      }
    }

    const int point = tile * PT + p;
    // qn/kn: sum of channel norms (Q and K mats only)
    if (mat < 2) {
      float nsum = 0.f;
      #pragma unroll
      for (int o = 0; o < 8; ++o)
        nsum += sqrtf(acc[o*3+0]*acc[o*3+0] + acc[o*3+1]*acc[o*3+1] + acc[o*3+2]*acc[o*3+2]);
      #pragma unroll
      for (int off = 8; off > 0; off >>= 1) nsum += __shfl_down(nsum, off, 16);
      if (og == 0) {
        if (mat == 0) qn[point] = nsum * (1.0f/128.0f);
        else          kn[point] = nsum * (1.0f/128.0f);
      }
    }

    float* op = Out + (size_t)point * (CC*3) + obase*3;
    #pragma unroll
    for (int i = 0; i < 6; ++i) {
      float4 f = {acc[i*4+0], acc[i*4+1], acc[i*4+2], acc[i*4+3]};
      ((float4*)op)[i] = f;
    }
  }
}

// ---------------------------------------------------------------------------
// Kernel 3: attention + message + VN layer norm + clamp. One block per point.
// ---------------------------------------------------------------------------
__global__ __launch_bounds__(256) void attn_kernel(
    const float* __restrict__ x, const int* __restrict__ idx,
    const float* __restrict__ Q, const float* __restrict__ Kt, const float* __restrict__ U,
    const float* __restrict__ qn, const float* __restrict__ kn,
    const float* __restrict__ W1, const float* __restrict__ b1,
    const float* __restrict__ W2, const float* __restrict__ b2,
    const float* __restrict__ W3, const float* __restrict__ b3,
    const float* __restrict__ gam, const float* __restrict__ bet,
    float* __restrict__ out)
{
  const int bn = blockIdx.x;
  const int b = bn >> 11;
  const int tid = threadIdx.x;

  __shared__ __align__(16) float qs[CC*3];
  __shared__ int   nbr[KNB];
  __shared__ float sfeat[KNB][4];
  __shared__ float h1s[KNB][33];
  __shared__ float logits[KNB];
  __shared__ float attnw[KNB];
  __shared__ float red[4];
  __shared__ float red2[4];

  const float* Qp = Q + (size_t)bn * (CC*3);
  if (tid < 96) ((float4*)qs)[tid] = ((const float4*)Qp)[tid];
  if (tid < KNB) nbr[tid] = idx[(size_t)bn * KNB + tid];
  __syncthreads();

  // Phase 1: Q.K dots (16 lanes per neighbor) + edge features
  {
    const int lane = tid & 63, wave = tid >> 6;
    const int kk = wave * 4 + (lane >> 4);
    const int sub = lane & 15;
    const int j = nbr[kk];
    const float* Kp = Kt + ((size_t)(b * NN + j)) * (CC*3);
    float acc = 0.f;
    #pragma unroll
    for (int q4 = 0; q4 < 6; ++q4) {
      const int off = sub * 24 + q4 * 4;
      float4 kv = *(const float4*)(Kp + off);
      acc += qs[off+0]*kv.x + qs[off+1]*kv.y + qs[off+2]*kv.z + qs[off+3]*kv.w;
    }
    #pragma unroll
    for (int off = 8; off > 0; off >>= 1) acc += __shfl_down(acc, off, 16);
    if (sub == 0) {
      const float xn0 = x[(size_t)bn*3+0], xn1 = x[(size_t)bn*3+1], xn2 = x[(size_t)bn*3+2];
      const size_t xj = (size_t)(b * NN + j) * 3;
      const float dx = xn0 - x[xj+0], dy = xn1 - x[xj+1], dz = xn2 - x[xj+2];
      sfeat[kk][0] = qn[bn];
      sfeat[kk][1] = kn[b * NN + j];
      sfeat[kk][2] = acc * (1.0f/128.0f);
      sfeat[kk][3] = sqrtf(dx*dx + dy*dy + dz*dz);
    }
  }
  __syncthreads();

  // Phase 2: edge MLP (16 neighbors x 16 threads)
  {
    const int k2 = tid >> 4;
    const int h = tid & 15;
    const float s0 = sfeat[k2][0], s1 = sfeat[k2][1], s2 = sfeat[k2][2], s3 = sfeat[k2][3];
    float u0 = b1[h]    + W1[h*4+0]*s0 + W1[h*4+1]*s1 + W1[h*4+2]*s2 + W1[h*4+3]*s3;
    float u1 = b1[h+16] + W1[(h+16)*4+0]*s0 + W1[(h+16)*4+1]*s1 + W1[(h+16)*4+2]*s2 + W1[(h+16)*4+3]*s3;
    h1s[k2][h]    = silu_f(u0);
    h1s[k2][h+16] = silu_f(u1);
  }
  __syncthreads();
  {
    const int k2 = tid >> 4;
    const int h = tid & 15;
    float a0 = b2[h], a1 = b2[h+16];
    #pragma unroll
    for (int c = 0; c < 32; ++c) {
      const float hv = h1s[k2][c];
      a0 = fmaf(W2[h*32+c], hv, a0);
      a1 = fmaf(W2[(h+16)*32+c], hv, a1);
    }
    a0 = silu_f(a0); a1 = silu_f(a1);
    float part = W3[h]*a0 + W3[h+16]*a1;
    #pragma unroll
    for (int off = 8; off > 0; off >>= 1) part += __shfl_down(part, off, 16);
    if (h == 0) {
      const float lg = part + b3[0];
      logits[k2] = fminf(fmaxf(lg, -10.0f), 10.0f);
    }
  }
  __syncthreads();

  // Phase 3: softmax over 16 neighbors
  if (tid < KNB) {
    const float l = logits[tid];
    float m = l;
    #pragma unroll
    for (int off = 8; off > 0; off >>= 1) m = fmaxf(m, __shfl_xor(m, off, 16));
    const float e = expf(l - m);
    float ssum = e;
    #pragma unroll
    for (int off = 8; off > 0; off >>= 1) ssum += __shfl_xor(ssum, off, 16);
    attnw[tid] = e / ssum;
  }
  __syncthreads();

  // Phase 4: message + residual + VN layer norm + clamp (thread = channel o)
  float o0 = 0.f, o1 = 0.f, o2 = 0.f, nrm = 0.f;
  const bool act = tid < CC;
  if (act) {
    const int o = tid;
    float m0 = 0.f, m1 = 0.f, m2 = 0.f;
    #pragma unroll
    for (int k2 = 0; k2 < KNB; ++k2) {
      const int j = nbr[k2];
      const float* Up = U + ((size_t)(b * NN + j)) * (CC*3) + o*3;
      const float a = attnw[k2];
      m0 = fmaf(a, Up[0], m0);
      m1 = fmaf(a, Up[1], m1);
      m2 = fmaf(a, Up[2], m2);
    }
    o0 = qs[o*3+0] + 0.5f*m0;
    o1 = qs[o*3+1] + 0.5f*m1;
    o2 = qs[o*3+2] + 0.5f*m2;
    nrm = fmaxf(sqrtf(o0*o0 + o1*o1 + o2*o2), 1e-6f);
  }
  {
    float s = nrm;
    #pragma unroll
    for (int off = 32; off > 0; off >>= 1) s += __shfl_down(s, off, 64);
    if ((tid & 63) == 0) red[tid >> 6] = s;
  }
  __syncthreads();
  const float mean = (red[0] + red[1] + red[2] + red[3]) * (1.0f/128.0f);
  const float dv = act ? (nrm - mean) : 0.f;
  {
    float s = dv * dv;
    #pragma unroll
    for (int off = 32; off > 0; off >>= 1) s += __shfl_down(s, off, 64);
    if ((tid & 63) == 0) red2[tid >> 6] = s;
  }
  __syncthreads();
  const float var = (red2[0] + red2[1] + red2[2] + red2[3]) * (1.0f/127.0f);
  const float stdv = fmaxf(sqrtf(var), 1e-6f);

  if (act) {
    const int o = tid;
    const float ns = (nrm - mean) / stdv * gam[o] + bet[o];
    const float sc1 = fmaxf(ns, 1e-6f) / nrm;
    float f0 = o0*sc1, f1 = o1*sc1, f2 = o2*sc1;
    const float n2 = fmaxf(sqrtf(f0*f0 + f1*f1 + f2*f2), 1e-6f);
    const float sc2 = fminf(50.0f / n2, 1.0f);
    float* op = out + (size_t)bn * (CC*3) + o*3;
    op[0] = f0*sc2; op[1] = f1*sc2; op[2] = f2*sc2;
  }
}

// ---------------------------------------------------------------------------
extern "C" void kernel_launch(void* const* d_in, const int* in_sizes, int n_in,
                              void* d_out, int out_size, void* d_ws, size_t ws_size,
                              hipStream_t stream) {
  (void)in_sizes; (void)n_in; (void)out_size; (void)ws_size;
  const float* x   = (const float*)d_in[0];
  const float* v   = (const float*)d_in[1];
  const float* Wq  = (const float*)d_in[2];
  const float* Wk  = (const float*)d_in[3];
  const float* Wu  = (const float*)d_in[4];
  const float* W1  = (const float*)d_in[5];
  const float* b1  = (const float*)d_in[6];
  const float* W2  = (const float*)d_in[7];
  const float* b2  = (const float*)d_in[8];
  const float* W3  = (const float*)d_in[9];
  const float* b3  = (const float*)d_in[10];
  const float* gam = (const float*)d_in[11];
  const float* bet = (const float*)d_in[12];
  float* out = (float*)d_out;

  char* ws = (char*)d_ws;
  int*   idx = (int*)ws;                                  // BN*16 ints (1 MB)
  float* Q   = (float*)(ws + (size_t)BN * KNB * 4);       // BN*384 floats
  float* Kt  = Q  + (size_t)BN * CC * 3;
  float* U   = Kt + (size_t)BN * CC * 3;
  float* qn  = U  + (size_t)BN * CC * 3;
  float* kn  = qn + BN;

  knn_kernel<<<BN, 256, 0, stream>>>(x, idx);
  vn_linear_gemm<<<dim3(256, 3), 256, 0, stream>>>(v, Wq, Wk, Wu, Q, Kt, U, qn, kn);
  attn_kernel<<<BN, 256, 0, stream>>>(x, idx, Q, Kt, U, qn, kn,
                                      W1, b1, W2, b2, W3, b3, gam, bet, out);
}

// Round 4
// 547.088 us; speedup vs baseline: 4.2917x; 1.2084x over previous
//
#include <hip/hip_runtime.h>
#include <math.h>

#define BB 8
#define NN 2048
#define CC 128
#define KNB 16
#define BN (BB*NN)
#define PT 16          // points per GEMM tile
#define WSROW 132      // padded LDS row for W (16B-aligned, spreads banks)

__device__ __forceinline__ float silu_f(float x) { return x / (1.0f + expf(-x)); }

// ---------------------------------------------------------------------------
// Kernel 1: kNN — one WAVE per query (64-thread block). f64 distances (exact
// ordering vs the f64 numpy reference). Tournament selection: each lane owns
// a 32-elem segment with its (min,argmin) in registers; per extraction do a
// 6-level butterfly over 64 segment minima, then rescan only the winning
// segment (32 elems, broadcast LDS reads). ~9x less scan work than full
// re-scans; no cross-wave barriers, no serialized merge.
// ---------------------------------------------------------------------------
__global__ __launch_bounds__(64) void knn_kernel(const float* __restrict__ x,
                                                 int* __restrict__ idx) {
  const int bn = blockIdx.x;
  const int b = bn >> 11;
  const int n = bn & (NN - 1);
  const int lane = threadIdx.x;

  __shared__ double d2s[64 * 33];   // lane-padded: elem m=i*64+lane at [lane*33+i]

  const float* xb = x + (size_t)b * NN * 3;
  const double xn0 = (double)xb[n*3+0], xn1 = (double)xb[n*3+1], xn2 = (double)xb[n*3+2];
  const double sqn = xn0*xn0 + xn1*xn1 + xn2*xn2;

  double segmin = (double)INFINITY;
  int    segidx = 0x7fffffff;
  #pragma unroll 4
  for (int i = 0; i < 32; ++i) {
    const int m = i*64 + lane;
    const double a0 = (double)xb[m*3+0], a1 = (double)xb[m*3+1], a2 = (double)xb[m*3+2];
    const double sqm = a0*a0 + a1*a1 + a2*a2;
    const double dot = xn0*a0 + xn1*a1 + xn2*a2;
    double d = sqn + sqm - 2.0*dot;
    if (m == n) d = (double)INFINITY;
    d2s[lane*33 + i] = d;
    if (d < segmin) { segmin = d; segidx = m; }   // ascending m => lowest idx on tie
  }
  __syncthreads();

  int* op = idx + (size_t)bn * KNB;
  for (int t = 0; t < KNB; ++t) {
    // global argmin over 64 segment minima (butterfly; all lanes converge)
    double bv = segmin; int bi = segidx;
    #pragma unroll
    for (int off = 32; off > 0; off >>= 1) {
      const double ov = __shfl_xor(bv, off, 64);
      const int    oi = __shfl_xor(bi, off, 64);
      if (ov < bv || (ov == bv && oi < bi)) { bv = ov; bi = oi; }
    }
    if (lane == 0) op[t] = bi;

    const int owner = bi & 63;
    const int islot = bi >> 6;
    if (lane == 0) d2s[owner*33 + islot] = (double)INFINITY;
    __syncthreads();

    // rescan winning segment: 32 elems, 2 lanes/elem (broadcast reads free)
    const int j = lane & 31;
    double dv = d2s[owner*33 + j];
    int    dm = j*64 + owner;
    #pragma unroll
    for (int off = 16; off > 0; off >>= 1) {
      const double ov = __shfl_xor(dv, off, 64);
      const int    oi = __shfl_xor(dm, off, 64);
      if (ov < dv || (ov == dv && oi < dm)) { dv = ov; dm = oi; }
    }
    if (lane == owner) { segmin = dv; segidx = dm; }
    __syncthreads();
  }
}

// ---------------------------------------------------------------------------
// Kernel 2: Q/K/U as LDS-tiled fp32 GEMM. W fully in LDS (Ws[c][o], padded
// row), V tile (16 points x 128c x 3d) in Vs[c][p*4+d]. Thread = (og, p):
// 8 o x 3 d = 24 accumulators. Register prefetch of next tile overlaps the
// k-loop. qn/kn (mean channel norms) computed in the epilogue.
// ---------------------------------------------------------------------------
__global__ __launch_bounds__(256) void vn_linear_gemm(
    const float* __restrict__ v,
    const float* __restrict__ Wq, const float* __restrict__ Wk, const float* __restrict__ Wu,
    float* __restrict__ Q, float* __restrict__ Kt, float* __restrict__ U,
    float* __restrict__ qn, float* __restrict__ kn)
{
  const int mat = blockIdx.y;
  const float* __restrict__ W = (mat == 0) ? Wq : ((mat == 1) ? Wk : Wu);
  float* __restrict__ Out = (mat == 0) ? Q : ((mat == 1) ? Kt : U);

  __shared__ float Ws[CC][WSROW];   // 67.6 KB: [c][o]
  __shared__ float Vs[CC][PT*4];    // 32 KB:   [c][p*4+d]

  const int tid = threadIdx.x;
  const int og = tid & 15;          // o = og*8 .. og*8+7
  const int p  = tid >> 4;          // point within tile
  const int obase = og * 8;

  // Load W[o][c] -> Ws[c][o] (one-time; coalesced global, stride-1-bank LDS writes)
  for (int i = tid; i < CC*CC; i += 256) {
    const int o = i >> 7, c = i & 127;
    Ws[c][o] = W[i];
  }

  float pre[24];
  const int t0 = blockIdx.x;        // tiles t0, t0+256, t0+512, t0+768
  {
    const float4* src = (const float4*)(v + (size_t)t0 * PT * (CC*3));
    #pragma unroll
    for (int it = 0; it < 6; ++it) {
      float4 f = src[tid + it*256];
      pre[it*4+0]=f.x; pre[it*4+1]=f.y; pre[it*4+2]=f.z; pre[it*4+3]=f.w;
    }
  }

  for (int tt = 0; tt < 4; ++tt) {
    const int tile = t0 + tt*256;
    __syncthreads();                // Vs free to overwrite (covers Ws on tt=0)
    #pragma unroll
    for (int it = 0; it < 6; ++it) {
      #pragma unroll
      for (int j = 0; j < 4; ++j) {
        const int g = (tid + it*256)*4 + j;
        const int pp = g / 384;
        const int r  = g - pp*384;
        const int c  = r / 3;
        const int d  = r - c*3;
        Vs[c][pp*4 + d] = pre[it*4+j];
      }
    }
    __syncthreads();

    if (tt < 3) {
      const float4* src = (const float4*)(v + (size_t)(tile + 256) * PT * (CC*3));
      #pragma unroll
      for (int it = 0; it < 6; ++it) {
        float4 f = src[tid + it*256];
        pre[it*4+0]=f.x; pre[it*4+1]=f.y; pre[it*4+2]=f.z; pre[it*4+3]=f.w;
      }
    }

    float acc[24];
    #pragma unroll
    for (int i = 0; i < 24; ++i) acc[i] = 0.f;

    #pragma unroll 4
    for (int c = 0; c < CC; ++c) {
      const float4 w0 = *(const float4*)&Ws[c][obase];
      const float4 w1 = *(const float4*)&Ws[c][obase+4];
      const float4 vv = *(const float4*)&Vs[c][p*4];
      const float wv[8] = {w0.x, w0.y, w0.z, w0.w, w1.x, w1.y, w1.z, w1.w};
      #pragma unroll
      for (int o = 0; o < 8; ++o) {
        acc[o*3+0] = fmaf(wv[o], vv.x, acc[o*3+0]);
        acc[o*3+1] = fmaf(wv[o], vv.y, acc[o*3+1]);
        acc[o*3+2] = fmaf(wv[o], vv.z, acc[o*3+2]);
      }
    }

    const int point = tile * PT + p;
    // qn/kn: sum of channel norms (Q and K mats only)
    if (mat < 2) {
      float nsum = 0.f;
      #pragma unroll
      for (int o = 0; o < 8; ++o)
        nsum += sqrtf(acc[o*3+0]*acc[o*3+0] + acc[o*3+1]*acc[o*3+1] + acc[o*3+2]*acc[o*3+2]);
      #pragma unroll
      for (int off = 8; off > 0; off >>= 1) nsum += __shfl_down(nsum, off, 16);
      if (og == 0) {
        if (mat == 0) qn[point] = nsum * (1.0f/128.0f);
        else          kn[point] = nsum * (1.0f/128.0f);
      }
    }

    float* op = Out + (size_t)point * (CC*3) + obase*3;
    #pragma unroll
    for (int i = 0; i < 6; ++i) {
      float4 f = {acc[i*4+0], acc[i*4+1], acc[i*4+2], acc[i*4+3]};
      ((float4*)op)[i] = f;
    }
  }
}

// ---------------------------------------------------------------------------
// Kernel 3: attention + message + VN layer norm + clamp. One block per point.
// ---------------------------------------------------------------------------
__global__ __launch_bounds__(256) void attn_kernel(
    const float* __restrict__ x, const int* __restrict__ idx,
    const float* __restrict__ Q, const float* __restrict__ Kt, const float* __restrict__ U,
    const float* __restrict__ qn, const float* __restrict__ kn,
    const float* __restrict__ W1, const float* __restrict__ b1,
    const float* __restrict__ W2, const float* __restrict__ b2,
    const float* __restrict__ W3, const float* __restrict__ b3,
    const float* __restrict__ gam, const float* __restrict__ bet,
    float* __restrict__ out)
{
  const int bn = blockIdx.x;
  const int b = bn >> 11;
  const int tid = threadIdx.x;

  __shared__ __align__(16) float qs[CC*3];
  __shared__ int   nbr[KNB];
  __shared__ float sfeat[KNB][4];
  __shared__ float h1s[KNB][33];
  __shared__ float logits[KNB];
  __shared__ float attnw[KNB];
  __shared__ float red[4];
  __shared__ float red2[4];

  const float* Qp = Q + (size_t)bn * (CC*3);
  if (tid < 96) ((float4*)qs)[tid] = ((const float4*)Qp)[tid];
  if (tid < KNB) nbr[tid] = idx[(size_t)bn * KNB + tid];
  __syncthreads();

  // Phase 1: Q.K dots (16 lanes per neighbor) + edge features
  {
    const int lane = tid & 63, wave = tid >> 6;
    const int kk = wave * 4 + (lane >> 4);
    const int sub = lane & 15;
    const int j = nbr[kk];
    const float* Kp = Kt + ((size_t)(b * NN + j)) * (CC*3);
    float acc = 0.f;
    #pragma unroll
    for (int q4 = 0; q4 < 6; ++q4) {
      const int off = sub * 24 + q4 * 4;
      float4 kv = *(const float4*)(Kp + off);
      acc += qs[off+0]*kv.x + qs[off+1]*kv.y + qs[off+2]*kv.z + qs[off+3]*kv.w;
    }
    #pragma unroll
    for (int off = 8; off > 0; off >>= 1) acc += __shfl_down(acc, off, 16);
    if (sub == 0) {
      const float xn0 = x[(size_t)bn*3+0], xn1 = x[(size_t)bn*3+1], xn2 = x[(size_t)bn*3+2];
      const size_t xj = (size_t)(b * NN + j) * 3;
      const float dx = xn0 - x[xj+0], dy = xn1 - x[xj+1], dz = xn2 - x[xj+2];
      sfeat[kk][0] = qn[bn];
      sfeat[kk][1] = kn[b * NN + j];
      sfeat[kk][2] = acc * (1.0f/128.0f);
      sfeat[kk][3] = sqrtf(dx*dx + dy*dy + dz*dz);
    }
  }
  __syncthreads();

  // Phase 2: edge MLP (16 neighbors x 16 threads)
  {
    const int k2 = tid >> 4;
    const int h = tid & 15;
    const float s0 = sfeat[k2][0], s1 = sfeat[k2][1], s2 = sfeat[k2][2], s3 = sfeat[k2][3];
    float u0 = b1[h]    + W1[h*4+0]*s0 + W1[h*4+1]*s1 + W1[h*4+2]*s2 + W1[h*4+3]*s3;
    float u1 = b1[h+16] + W1[(h+16)*4+0]*s0 + W1[(h+16)*4+1]*s1 + W1[(h+16)*4+2]*s2 + W1[(h+16)*4+3]*s3;
    h1s[k2][h]    = silu_f(u0);
    h1s[k2][h+16] = silu_f(u1);
  }
  __syncthreads();
  {
    const int k2 = tid >> 4;
    const int h = tid & 15;
    float a0 = b2[h], a1 = b2[h+16];
    #pragma unroll
    for (int c = 0; c < 32; ++c) {
      const float hv = h1s[k2][c];
      a0 = fmaf(W2[h*32+c], hv, a0);
      a1 = fmaf(W2[(h+16)*32+c], hv, a1);
    }
    a0 = silu_f(a0); a1 = silu_f(a1);
    float part = W3[h]*a0 + W3[h+16]*a1;
    #pragma unroll
    for (int off = 8; off > 0; off >>= 1) part += __shfl_down(part, off, 16);
    if (h == 0) {
      const float lg = part + b3[0];
      logits[k2] = fminf(fmaxf(lg, -10.0f), 10.0f);
    }
  }
  __syncthreads();

  // Phase 3: softmax over 16 neighbors
  if (tid < KNB) {
    const float l = logits[tid];
    float m = l;
    #pragma unroll
    for (int off = 8; off > 0; off >>= 1) m = fmaxf(m, __shfl_xor(m, off, 16));
    const float e = expf(l - m);
    float ssum = e;
    #pragma unroll
    for (int off = 8; off > 0; off >>= 1) ssum += __shfl_xor(ssum, off, 16);
    attnw[tid] = e / ssum;
  }
  __syncthreads();

  // Phase 4: message + residual + VN layer norm + clamp (thread = channel o)
  float o0 = 0.f, o1 = 0.f, o2 = 0.f, nrm = 0.f;
  const bool act = tid < CC;
  if (act) {
    const int o = tid;
    float m0 = 0.f, m1 = 0.f, m2 = 0.f;
    #pragma unroll
    for (int k2 = 0; k2 < KNB; ++k2) {
      const int j = nbr[k2];
      const float* Up = U + ((size_t)(b * NN + j)) * (CC*3) + o*3;
      const float a = attnw[k2];
      m0 = fmaf(a, Up[0], m0);
      m1 = fmaf(a, Up[1], m1);
      m2 = fmaf(a, Up[2], m2);
    }
    o0 = qs[o*3+0] + 0.5f*m0;
    o1 = qs[o*3+1] + 0.5f*m1;
    o2 = qs[o*3+2] + 0.5f*m2;
    nrm = fmaxf(sqrtf(o0*o0 + o1*o1 + o2*o2), 1e-6f);
  }
  {
    float s = nrm;
    #pragma unroll
    for (int off = 32; off > 0; off >>= 1) s += __shfl_down(s, off, 64);
    if ((tid & 63) == 0) red[tid >> 6] = s;
  }
  __syncthreads();
  const float mean = (red[0] + red[1] + red[2] + red[3]) * (1.0f/128.0f);
  const float dv = act ? (nrm - mean) : 0.f;
  {
    float s = dv * dv;
    #pragma unroll
    for (int off = 32; off > 0; off >>= 1) s += __shfl_down(s, off, 64);
    if ((tid & 63) == 0) red2[tid >> 6] = s;
  }
  __syncthreads();
  const float var = (red2[0] + red2[1] + red2[2] + red2[3]) * (1.0f/127.0f);
  const float stdv = fmaxf(sqrtf(var), 1e-6f);

  if (act) {
    const int o = tid;
    const float ns = (nrm - mean) / stdv * gam[o] + bet[o];
    const float sc1 = fmaxf(ns, 1e-6f) / nrm;
    float f0 = o0*sc1, f1 = o1*sc1, f2 = o2*sc1;
    const float n2 = fmaxf(sqrtf(f0*f0 + f1*f1 + f2*f2), 1e-6f);
    const float sc2 = fminf(50.0f / n2, 1.0f);
    float* op = out + (size_t)bn * (CC*3) + o*3;
    op[0] = f0*sc2; op[1] = f1*sc2; op[2] = f2*sc2;
  }
}

// ---------------------------------------------------------------------------
extern "C" void kernel_launch(void* const* d_in, const int* in_sizes, int n_in,
                              void* d_out, int out_size, void* d_ws, size_t ws_size,
                              hipStream_t stream) {
  (void)in_sizes; (void)n_in; (void)out_size; (void)ws_size;
  const float* x   = (const float*)d_in[0];
  const float* v   = (const float*)d_in[1];
  const float* Wq  = (const float*)d_in[2];
  const float* Wk  = (const float*)d_in[3];
  const float* Wu  = (const float*)d_in[4];
  const float* W1  = (const float*)d_in[5];
  const float* b1  = (const float*)d_in[6];
  const float* W2  = (const float*)d_in[7];
  const float* b2  = (const float*)d_in[8];
  const float* W3  = (const float*)d_in[9];
  const float* b3  = (const float*)d_in[10];
  const float* gam = (const float*)d_in[11];
  const float* bet = (const float*)d_in[12];
  float* out = (float*)d_out;

  char* ws = (char*)d_ws;
  int*   idx = (int*)ws;                                  // BN*16 ints (1 MB)
  float* Q   = (float*)(ws + (size_t)BN * KNB * 4);       // BN*384 floats
  float* Kt  = Q  + (size_t)BN * CC * 3;
  float* U   = Kt + (size_t)BN * CC * 3;
  float* qn  = U  + (size_t)BN * CC * 3;
  float* kn  = qn + BN;

  knn_kernel<<<BN, 64, 0, stream>>>(x, idx);
  vn_linear_gemm<<<dim3(256, 3), 256, 0, stream>>>(v, Wq, Wk, Wu, Q, Kt, U, qn, kn);
  attn_kernel<<<BN, 256, 0, stream>>>(x, idx, Q, Kt, U, qn, kn,
                                      W1, b1, W2, b2, W3, b3, gam, bet, out);
}

// Round 5
// 431.192 us; speedup vs baseline: 5.4452x; 1.2688x over previous
//
#include <hip/hip_runtime.h>
#include <math.h>

#define BB 8
#define NN 2048
#define CC 128
#define KNB 16
#define BN (BB*NN)
#define PT 16          // points per GEMM tile
#define WSROW 132      // padded LDS row for W (16B-aligned, spreads banks)

#define EMPTYK 0xFFFFFFFFFFFFFFFFULL

__device__ __forceinline__ float silu_f(float x) { return x / (1.0f + expf(-x)); }

__device__ __forceinline__ unsigned long long umin64(unsigned long long a, unsigned long long b) {
  return (b < a) ? b : a;
}

// ---------------------------------------------------------------------------
// Kernel 1: kNN — one WAVE per query, 4 waves per 256-thread block, NO LDS,
// NO barriers. Packed key = (f64(d2) bits & ~2047) | m : u64-monotone on d2
// (d2>=0), unique, lower-index tie-break built in. Each lane holds its 32
// segment keys in VGPRs + a sorted top-4; extraction = 6-level u64 butterfly
// + masked shift in the owner lane; rare refill (lane yields 5th winner,
// P~2.6e-4/query) rescans registers with k > g exclusion.
// ---------------------------------------------------------------------------
__global__ __launch_bounds__(256) void knn_kernel(const float* __restrict__ x,
                                                  int* __restrict__ idx) {
  const int lane = threadIdx.x & 63;
  const int wave = threadIdx.x >> 6;
  const int bn = blockIdx.x * 4 + wave;
  const int b = bn >> 11;
  const int n = bn & (NN - 1);

  const float* xb = x + (size_t)b * NN * 3;
  const double xn0 = (double)xb[n*3+0], xn1 = (double)xb[n*3+1], xn2 = (double)xb[n*3+2];
  const double sqn = xn0*xn0 + xn1*xn1 + xn2*xn2;

  unsigned long long k[32];
  unsigned long long t0 = EMPTYK, t1 = EMPTYK, t2 = EMPTYK, t3 = EMPTYK;

  #pragma unroll
  for (int i = 0; i < 32; ++i) {
    const int m = i*64 + lane;
    const double a0 = (double)xb[m*3+0], a1 = (double)xb[m*3+1], a2 = (double)xb[m*3+2];
    const double sqm = a0*a0 + a1*a1 + a2*a2;
    const double dot = xn0*a0 + xn1*a1 + xn2*a2;
    const double d = sqn + sqm - 2.0*dot;
    unsigned long long kk =
        ((unsigned long long)__double_as_longlong(d) & ~2047ULL) | (unsigned long long)m;
    if (m == n) kk = 0x8000000000000000ULL | (unsigned long long)m;  // self: > all finite keys, != EMPTYK
    k[i] = kk;
    // branchless sorted-insert into t0<=t1<=t2<=t3
    const bool l3 = kk < t3, l2 = kk < t2, l1 = kk < t1, l0 = kk < t0;
    t3 = l3 ? (l2 ? t2 : kk) : t3;
    t2 = l2 ? (l1 ? t1 : kk) : t2;
    t1 = l1 ? (l0 ? t0 : kk) : t1;
    t0 = l0 ? kk : t0;
  }

  int* op = idx + (size_t)bn * KNB;
  for (int t = 0; t < KNB; ++t) {
    // global min over 64 lane-minima (u64 butterfly)
    unsigned long long g = t0;
    #pragma unroll
    for (int off = 32; off > 0; off >>= 1)
      g = umin64(g, (unsigned long long)__shfl_xor((unsigned long long)g, off, 64));

    if (lane == 0) op[t] = (int)(g & 2047ULL);

    // owner lane pops its queue
    const bool own = (t0 == g);
    t0 = own ? t1 : t0;
    t1 = own ? t2 : t1;
    t2 = own ? t3 : t2;
    t3 = own ? EMPTYK : t3;

    // rare refill: owner exhausted its top-4
    const bool need = (t0 == EMPTYK);
    if (__any(need)) {
      unsigned long long nm = EMPTYK;
      #pragma unroll
      for (int i = 0; i < 32; ++i) {
        const unsigned long long c = (k[i] > g) ? k[i] : EMPTYK;
        nm = umin64(nm, c);
      }
      t0 = need ? nm : t0;
    }
  }
}

// ---------------------------------------------------------------------------
// Kernel 2: Q/K/U as LDS-tiled fp32 GEMM. W fully in LDS (Ws[c][o], padded
// row), V tile (16 points x 128c x 3d) in Vs[c][p*4+d]. Thread = (og, p):
// 8 o x 3 d = 24 accumulators. Register prefetch of next tile overlaps the
// k-loop. qn/kn (mean channel norms) computed in the epilogue.
// ---------------------------------------------------------------------------
__global__ __launch_bounds__(256) void vn_linear_gemm(
    const float* __restrict__ v,
    const float* __restrict__ Wq, const float* __restrict__ Wk, const float* __restrict__ Wu,
    float* __restrict__ Q, float* __restrict__ Kt, float* __restrict__ U,
    float* __restrict__ qn, float* __restrict__ kn)
{
  const int mat = blockIdx.y;
  const float* __restrict__ W = (mat == 0) ? Wq : ((mat == 1) ? Wk : Wu);
  float* __restrict__ Out = (mat == 0) ? Q : ((mat == 1) ? Kt : U);

  __shared__ float Ws[CC][WSROW];   // 67.6 KB: [c][o]
  __shared__ float Vs[CC][PT*4];    // 32 KB:   [c][p*4+d]

  const int tid = threadIdx.x;
  const int og = tid & 15;          // o = og*8 .. og*8+7
  const int p  = tid >> 4;          // point within tile
  const int obase = og * 8;

  // Load W[o][c] -> Ws[c][o] (one-time; coalesced global, stride-1-bank LDS writes)
  for (int i = tid; i < CC*CC; i += 256) {
    const int o = i >> 7, c = i & 127;
    Ws[c][o] = W[i];
  }

  float pre[24];
  const int t0 = blockIdx.x;        // tiles t0, t0+256, t0+512, t0+768
  {
    const float4* src = (const float4*)(v + (size_t)t0 * PT * (CC*3));
    #pragma unroll
    for (int it = 0; it < 6; ++it) {
      float4 f = src[tid + it*256];
      pre[it*4+0]=f.x; pre[it*4+1]=f.y; pre[it*4+2]=f.z; pre[it*4+3]=f.w;
    }
  }

  for (int tt = 0; tt < 4; ++tt) {
    const int tile = t0 + tt*256;
    __syncthreads();                // Vs free to overwrite (covers Ws on tt=0)
    #pragma unroll
    for (int it = 0; it < 6; ++it) {
      #pragma unroll
      for (int j = 0; j < 4; ++j) {
        const int g = (tid + it*256)*4 + j;
        const int pp = g / 384;
        const int r  = g - pp*384;
        const int c  = r / 3;
        const int d  = r - c*3;
        Vs[c][pp*4 + d] = pre[it*4+j];
      }
    }
    __syncthreads();

    if (tt < 3) {
      const float4* src = (const float4*)(v + (size_t)(tile + 256) * PT * (CC*3));
      #pragma unroll
      for (int it = 0; it < 6; ++it) {
        float4 f = src[tid + it*256];
        pre[it*4+0]=f.x; pre[it*4+1]=f.y; pre[it*4+2]=f.z; pre[it*4+3]=f.w;
      }
    }

    float acc[24];
    #pragma unroll
    for (int i = 0; i < 24; ++i) acc[i] = 0.f;

    #pragma unroll 4
    for (int c = 0; c < CC; ++c) {
      const float4 w0 = *(const float4*)&Ws[c][obase];
      const float4 w1 = *(const float4*)&Ws[c][obase+4];
      const float4 vv = *(const float4*)&Vs[c][p*4];
      const float wv[8] = {w0.x, w0.y, w0.z, w0.w, w1.x, w1.y, w1.z, w1.w};
      #pragma unroll
      for (int o = 0; o < 8; ++o) {
        acc[o*3+0] = fmaf(wv[o], vv.x, acc[o*3+0]);
        acc[o*3+1] = fmaf(wv[o], vv.y, acc[o*3+1]);
        acc[o*3+2] = fmaf(wv[o], vv.z, acc[o*3+2]);
      }
    }

    const int point = tile * PT + p;
    // qn/kn: sum of channel norms (Q and K mats only)
    if (mat < 2) {
      float nsum = 0.f;
      #pragma unroll
      for (int o = 0; o < 8; ++o)
        nsum += sqrtf(acc[o*3+0]*acc[o*3+0] + acc[o*3+1]*acc[o*3+1] + acc[o*3+2]*acc[o*3+2]);
      #pragma unroll
      for (int off = 8; off > 0; off >>= 1) nsum += __shfl_down(nsum, off, 16);
      if (og == 0) {
        if (mat == 0) qn[point] = nsum * (1.0f/128.0f);
        else          kn[point] = nsum * (1.0f/128.0f);
      }
    }

    float* opt = Out + (size_t)point * (CC*3) + obase*3;
    #pragma unroll
    for (int i = 0; i < 6; ++i) {
      float4 f = {acc[i*4+0], acc[i*4+1], acc[i*4+2], acc[i*4+3]};
      ((float4*)opt)[i] = f;
    }
  }
}

// ---------------------------------------------------------------------------
// Kernel 3: attention + message + VN layer norm + clamp. One block per point.
// XCD-aware swizzle: blockIdx % 8 -> XCD (round-robin), so each XCD works on
// one batch (6 MB K+U working set vs 48 MB) for L2 locality.
// ---------------------------------------------------------------------------
__global__ __launch_bounds__(256) void attn_kernel(
    const float* __restrict__ x, const int* __restrict__ idx,
    const float* __restrict__ Q, const float* __restrict__ Kt, const float* __restrict__ U,
    const float* __restrict__ qn, const float* __restrict__ kn,
    const float* __restrict__ W1, const float* __restrict__ b1,
    const float* __restrict__ W2, const float* __restrict__ b2,
    const float* __restrict__ W3, const float* __restrict__ b3,
    const float* __restrict__ gam, const float* __restrict__ bet,
    float* __restrict__ out)
{
  const int bid = blockIdx.x;
  const int bn = ((bid & 7) << 11) | (bid >> 3);   // batch = bid%8 = XCD id
  const int b = bn >> 11;
  const int tid = threadIdx.x;

  __shared__ __align__(16) float qs[CC*3];
  __shared__ int   nbr[KNB];
  __shared__ float sfeat[KNB][4];
  __shared__ float h1s[KNB][33];
  __shared__ float logits[KNB];
  __shared__ float attnw[KNB];
  __shared__ float red[4];
  __shared__ float red2[4];

  const float* Qp = Q + (size_t)bn * (CC*3);
  if (tid < 96) ((float4*)qs)[tid] = ((const float4*)Qp)[tid];
  if (tid < KNB) nbr[tid] = idx[(size_t)bn * KNB + tid];
  __syncthreads();

  // Phase 1: Q.K dots (16 lanes per neighbor) + edge features
  {
    const int lane = tid & 63, wave = tid >> 6;
    const int kk = wave * 4 + (lane >> 4);
    const int sub = lane & 15;
    const int j = nbr[kk];
    const float* Kp = Kt + ((size_t)(b * NN + j)) * (CC*3);
    float acc = 0.f;
    #pragma unroll
    for (int q4 = 0; q4 < 6; ++q4) {
      const int off = sub * 24 + q4 * 4;
      float4 kv = *(const float4*)(Kp + off);
      acc += qs[off+0]*kv.x + qs[off+1]*kv.y + qs[off+2]*kv.z + qs[off+3]*kv.w;
    }
    #pragma unroll
    for (int off = 8; off > 0; off >>= 1) acc += __shfl_down(acc, off, 16);
    if (sub == 0) {
      const float xn0 = x[(size_t)bn*3+0], xn1 = x[(size_t)bn*3+1], xn2 = x[(size_t)bn*3+2];
      const size_t xj = (size_t)(b * NN + j) * 3;
      const float dx = xn0 - x[xj+0], dy = xn1 - x[xj+1], dz = xn2 - x[xj+2];
      sfeat[kk][0] = qn[bn];
      sfeat[kk][1] = kn[b * NN + j];
      sfeat[kk][2] = acc * (1.0f/128.0f);
      sfeat[kk][3] = sqrtf(dx*dx + dy*dy + dz*dz);
    }
  }
  __syncthreads();

  // Phase 2: edge MLP (16 neighbors x 16 threads)
  {
    const int k2 = tid >> 4;
    const int h = tid & 15;
    const float s0 = sfeat[k2][0], s1 = sfeat[k2][1], s2 = sfeat[k2][2], s3 = sfeat[k2][3];
    float u0 = b1[h]    + W1[h*4+0]*s0 + W1[h*4+1]*s1 + W1[h*4+2]*s2 + W1[h*4+3]*s3;
    float u1 = b1[h+16] + W1[(h+16)*4+0]*s0 + W1[(h+16)*4+1]*s1 + W1[(h+16)*4+2]*s2 + W1[(h+16)*4+3]*s3;
    h1s[k2][h]    = silu_f(u0);
    h1s[k2][h+16] = silu_f(u1);
  }
  __syncthreads();
  {
    const int k2 = tid >> 4;
    const int h = tid & 15;
    float a0 = b2[h], a1 = b2[h+16];
    #pragma unroll
    for (int c = 0; c < 32; ++c) {
      const float hv = h1s[k2][c];
      a0 = fmaf(W2[h*32+c], hv, a0);
      a1 = fmaf(W2[(h+16)*32+c], hv, a1);
    }
    a0 = silu_f(a0); a1 = silu_f(a1);
    float part = W3[h]*a0 + W3[h+16]*a1;
    #pragma unroll
    for (int off = 8; off > 0; off >>= 1) part += __shfl_down(part, off, 16);
    if (h == 0) {
      const float lg = part + b3[0];
      logits[k2] = fminf(fmaxf(lg, -10.0f), 10.0f);
    }
  }
  __syncthreads();

  // Phase 3: softmax over 16 neighbors
  if (tid < KNB) {
    const float l = logits[tid];
    float m = l;
    #pragma unroll
    for (int off = 8; off > 0; off >>= 1) m = fmaxf(m, __shfl_xor(m, off, 16));
    const float e = expf(l - m);
    float ssum = e;
    #pragma unroll
    for (int off = 8; off > 0; off >>= 1) ssum += __shfl_xor(ssum, off, 16);
    attnw[tid] = e / ssum;
  }
  __syncthreads();

  // Phase 4: message + residual + VN layer norm + clamp (thread = channel o)
  float o0 = 0.f, o1 = 0.f, o2 = 0.f, nrm = 0.f;
  const bool act = tid < CC;
  if (act) {
    const int o = tid;
    float m0 = 0.f, m1 = 0.f, m2 = 0.f;
    #pragma unroll
    for (int k2 = 0; k2 < KNB; ++k2) {
      const int j = nbr[k2];
      const float* Up = U + ((size_t)(b * NN + j)) * (CC*3) + o*3;
      const float a = attnw[k2];
      m0 = fmaf(a, Up[0], m0);
      m1 = fmaf(a, Up[1], m1);
      m2 = fmaf(a, Up[2], m2);
    }
    o0 = qs[o*3+0] + 0.5f*m0;
    o1 = qs[o*3+1] + 0.5f*m1;
    o2 = qs[o*3+2] + 0.5f*m2;
    nrm = fmaxf(sqrtf(o0*o0 + o1*o1 + o2*o2), 1e-6f);
  }
  {
    float s = nrm;
    #pragma unroll
    for (int off = 32; off > 0; off >>= 1) s += __shfl_down(s, off, 64);
    if ((tid & 63) == 0) red[tid >> 6] = s;
  }
  __syncthreads();
  const float mean = (red[0] + red[1] + red[2] + red[3]) * (1.0f/128.0f);
  const float dv = act ? (nrm - mean) : 0.f;
  {
    float s = dv * dv;
    #pragma unroll
    for (int off = 32; off > 0; off >>= 1) s += __shfl_down(s, off, 64);
    if ((tid & 63) == 0) red2[tid >> 6] = s;
  }
  __syncthreads();
  const float var = (red2[0] + red2[1] + red2[2] + red2[3]) * (1.0f/127.0f);
  const float stdv = fmaxf(sqrtf(var), 1e-6f);

  if (act) {
    const int o = tid;
    const float ns = (nrm - mean) / stdv * gam[o] + bet[o];
    const float sc1 = fmaxf(ns, 1e-6f) / nrm;
    float f0 = o0*sc1, f1 = o1*sc1, f2 = o2*sc1;
    const float n2 = fmaxf(sqrtf(f0*f0 + f1*f1 + f2*f2), 1e-6f);
    const float sc2 = fminf(50.0f / n2, 1.0f);
    float* op = out + (size_t)bn * (CC*3) + o*3;
    op[0] = f0*sc2; op[1] = f1*sc2; op[2] = f2*sc2;
  }
}

// ---------------------------------------------------------------------------
extern "C" void kernel_launch(void* const* d_in, const int* in_sizes, int n_in,
                              void* d_out, int out_size, void* d_ws, size_t ws_size,
                              hipStream_t stream) {
  (void)in_sizes; (void)n_in; (void)out_size; (void)ws_size;
  const float* x   = (const float*)d_in[0];
  const float* v   = (const float*)d_in[1];
  const float* Wq  = (const float*)d_in[2];
  const float* Wk  = (const float*)d_in[3];
  const float* Wu  = (const float*)d_in[4];
  const float* W1  = (const float*)d_in[5];
  const float* b1  = (const float*)d_in[6];
  const float* W2  = (const float*)d_in[7];
  const float* b2  = (const float*)d_in[8];
  const float* W3  = (const float*)d_in[9];
  const float* b3  = (const float*)d_in[10];
  const float* gam = (const float*)d_in[11];
  const float* bet = (const float*)d_in[12];
  float* out = (float*)d_out;

  char* ws = (char*)d_ws;
  int*   idx = (int*)ws;                                  // BN*16 ints (1 MB)
  float* Q   = (float*)(ws + (size_t)BN * KNB * 4);       // BN*384 floats
  float* Kt  = Q  + (size_t)BN * CC * 3;
  float* U   = Kt + (size_t)BN * CC * 3;
  float* qn  = U  + (size_t)BN * CC * 3;
  float* kn  = qn + BN;

  knn_kernel<<<BN/4, 256, 0, stream>>>(x, idx);
  vn_linear_gemm<<<dim3(256, 3), 256, 0, stream>>>(v, Wq, Wk, Wu, Q, Kt, U, qn, kn);
  attn_kernel<<<BN, 256, 0, stream>>>(x, idx, Q, Kt, U, qn, kn,
                                      W1, b1, W2, b2, W3, b3, gam, bet, out);
}